// Round 13
// baseline (160.276 us; speedup 1.0000x reference)
//
#include <hip/hip_runtime.h>

#define T_N   131072
#define K_N   64
#define L_C   64
#define F_N   8
#define N_CH  (T_N / L_C)   /* 2048 chunks per direction */
#define WARM  32
#define EPS_F 1e-10f
#define OBS_MAX ((T_N - 1) * F_N)

#define LOG2E 1.4426950408889634f
#define NL2E  (-0.72134752044448170f)
#define LN2   0.6931471805599453f
#define LN2PI 1.8378770664093453f
/* warm-up-only emission pre-scale 2^16 (round-2: store phase must stay at
   RAW emission scale to reproduce reference EPS saturation). WARM=32 (r9:
   16 visibly truncates). launch_bounds (64,2): allocator budgets 2x the
   declared waves (r10/r11 rule) -> 128 regs; working set ~110 fits.
   Round-13 theory: VALUBusy pinned at ~56% across 2/4/8 chains/SIMD while
   per-step latency scaled 468->907ns with waves/CU => the per-step LDS
   round-trip is a contended per-CU DS queue. This MATVEC has ZERO per-step
   DS ops: DPP within-row gather (r3-proven) + ki-ordered Tq (no splats) +
   polarity-independent permlane exchanges (psum(x)-x sub trick). */
#define EMSC  16.0f

typedef float v2f __attribute__((ext_vector_type(2)));
typedef unsigned uint2v __attribute__((ext_vector_type(2)));

#define DPPI(SRC, CTRL) __builtin_amdgcn_update_dpp(0, (SRC), (CTRL), 0xF, 0xF, true)
#define DPPF(SRC, CTRL) __int_as_float(DPPI(__float_as_int(SRC), (CTRL)))

/* ---- DPP wave64 sum: VALU-only ---- */
template <int CTRL>
__device__ __forceinline__ float dpp_add(float x) {
  int y = __builtin_amdgcn_update_dpp(0, __float_as_int(x), CTRL, 0xF, 0xF, true);
  return x + __int_as_float(y);
}
__device__ __forceinline__ float wave_sum64(float x) {
  x = dpp_add<0x111>(x);
  x = dpp_add<0x112>(x);
  x = dpp_add<0x114>(x);
  x = dpp_add<0x118>(x);
  x = dpp_add<0x142>(x);
  x = dpp_add<0x143>(x);
  return __int_as_float(__builtin_amdgcn_readlane(__float_as_int(x), 63));
}

/* polarity-independent butterfly sums (r3 silicon-proven): {d,s}=swap(x,x)
   -> d+s == x + x[lane^16] (resp ^32) under every exchange convention. */
#if __has_builtin(__builtin_amdgcn_permlane16_swap) && \
    __has_builtin(__builtin_amdgcn_permlane32_swap)
__device__ __forceinline__ float psum16(float x) {
  uint2v r = __builtin_amdgcn_permlane16_swap(__float_as_uint(x),
                                              __float_as_uint(x), false, false);
  return __uint_as_float(r.x) + __uint_as_float(r.y);
}
__device__ __forceinline__ float psum32(float x) {
  uint2v r = __builtin_amdgcn_permlane32_swap(__float_as_uint(x),
                                              __float_as_uint(x), false, false);
  return __uint_as_float(r.x) + __uint_as_float(r.y);
}
#else
__device__ __forceinline__ float psum16(float x) {
  return x + __int_as_float(
      __builtin_amdgcn_ds_swizzle(__float_as_int(x), 0x401F));
}
__device__ __forceinline__ float psum32(float x) {
  int addr = (((int)threadIdx.x ^ 32) & 63) << 2;
  return x + __int_as_float(
      __builtin_amdgcn_ds_bpermute(addr, __float_as_int(x)));
}
#endif

#define PKFMA(a, b, c) __builtin_elementwise_fma(a, b, c)
#define RCP(x) __builtin_amdgcn_rcpf(x)

/* emission: exp2(cc + sum_f x*(x*civ + cmiv)); coeffs pre-scaled by -0.5*log2e */
__device__ __forceinline__ float em_pk(const float4& xa, const float4& xb,
                                       const v2f civ2[4], const v2f cmiv2[4],
                                       float cc) {
  v2f x0 = {xa.x, xa.y}, x1 = {xa.z, xa.w};
  v2f x2 = {xb.x, xb.y}, x3 = {xb.z, xb.w};
  v2f a0 = {cc, 0.f}, a1 = {0.f, 0.f};
  a0 = PKFMA(x0, PKFMA(x0, civ2[0], cmiv2[0]), a0);
  a1 = PKFMA(x1, PKFMA(x1, civ2[1], cmiv2[1]), a1);
  a0 = PKFMA(x2, PKFMA(x2, civ2[2], cmiv2[2]), a0);
  a1 = PKFMA(x3, PKFMA(x3, civ2[3], cmiv2[3]), a1);
  v2f s = a0 + a1;
  return __builtin_amdgcn_exp2f(s.x + s.y);
}

/* 64x64 matvec, ZERO per-step DS ops.
   Quarter decomposition (r7-proven): lane l computes X_d = partial of row
   l^16d over its own 16-state group's columns; y[l] = X0[l] + X1[l^16] +
   X2[l^32] + X3[l^48].
   Front-end: 15-op DPP within-row gather (r3-proven chain; ROW_ROR4/8 +
   quad perms = true 16-permutation). Gr[rr] = v[ki[rr]]; Tq is preloaded
   in ki ORDER so pairs {Gr[2j],Gr[2j+1]} feed pk_fma directly (no splats).
   Combine: pure exchanges built from the polarity-independent psum:
   exch(x) = psum(x) - x (exact to 1 ulp). */
#define MATVEC(VV, MOUT)                                                      \
  {                                                                           \
    float Gr[16];                                                             \
    Gr[0] = (VV);                                                             \
    Gr[1] = DPPF(Gr[0], 0xB1);                                                \
    Gr[2] = DPPF(Gr[0], 0x4E);                                                \
    Gr[3] = DPPF(Gr[1], 0x4E);                                                \
    _Pragma("unroll")                                                         \
    for (int rr = 0; rr < 4; ++rr) Gr[4 + rr] = DPPF(Gr[rr], 0x124);          \
    _Pragma("unroll")                                                         \
    for (int rr = 0; rr < 8; ++rr) Gr[8 + rr] = DPPF(Gr[rr], 0x128);          \
    v2f g_[8];                                                                \
    _Pragma("unroll")                                                         \
    for (int j_ = 0; j_ < 8; ++j_) g_[j_] = (v2f){Gr[2 * j_], Gr[2 * j_ + 1]};\
    float X0_, X1_, X2_, X3_;                                                 \
    _Pragma("unroll")                                                         \
    for (int d_ = 0; d_ < 4; ++d_) {                                          \
      v2f aA_ = {0.f, 0.f}, aB_ = {0.f, 0.f};                                 \
      aA_ = PKFMA(g_[0], Tq[d_][0], aA_);                                     \
      aB_ = PKFMA(g_[1], Tq[d_][1], aB_);                                     \
      aA_ = PKFMA(g_[2], Tq[d_][2], aA_);                                     \
      aB_ = PKFMA(g_[3], Tq[d_][3], aB_);                                     \
      aA_ = PKFMA(g_[4], Tq[d_][4], aA_);                                     \
      aB_ = PKFMA(g_[5], Tq[d_][5], aB_);                                     \
      aA_ = PKFMA(g_[6], Tq[d_][6], aA_);                                     \
      aB_ = PKFMA(g_[7], Tq[d_][7], aB_);                                     \
      v2f s_ = aA_ + aB_;                                                     \
      float xs_ = s_.x + s_.y;                                                \
      if (d_ == 0) X0_ = xs_;                                                 \
      else if (d_ == 1) X1_ = xs_;                                            \
      else if (d_ == 2) X2_ = xs_;                                            \
      else X3_ = xs_;                                                         \
    }                                                                         \
    float e1_ = psum16(X1_) - X1_;             /* X1[l^16] */                 \
    float R_  = X2_ + (psum16(X3_) - X3_);     /* X2 + X3[l^16] */            \
    float e2_ = psum32(R_) - R_;               /* X2[l^32] + X3[l^48] */      \
    MOUT = (X0_ + e1_) + e2_;                                                 \
  }

extern "C" __global__ void __launch_bounds__(64, 2)
hdphmm_fb(const float* __restrict__ obs,
          const float* __restrict__ beta_logits,
          const float* __restrict__ pi_logits,
          const float* __restrict__ means,
          const float* __restrict__ log_vars,
          float* __restrict__ out) {
  const int lane = threadIdx.x;
  const int bid  = blockIdx.x;

  __shared__ __align__(8) float2 sstat[K_N];
  __shared__ float sb[K_N];

  float* alpha   = out;
  float* betaout = out + (size_t)T_N * K_N;

  /* ---- per-lane emission coefficients (lane == state), packed ---- */
  v2f civ2[4], cmiv2[4];
  float c0, cw;
  {
    const float4* mp = reinterpret_cast<const float4*>(means + lane * F_N);
    const float4* lp = reinterpret_cast<const float4*>(log_vars + lane * F_N);
    float4 m0 = mp[0], m1 = mp[1];
    float4 l0 = lp[0], l1 = lp[1];
    float mu[8] = {m0.x, m0.y, m0.z, m0.w, m1.x, m1.y, m1.z, m1.w};
    float lv[8] = {l0.x, l0.y, l0.z, l0.w, l1.x, l1.y, l1.z, l1.w};
    float cst = F_N * LN2PI;
#pragma unroll
    for (int f = 0; f < 8; ++f) {
      float iv = __builtin_amdgcn_exp2f(-lv[f] * LOG2E);
      cst += lv[f] + mu[f] * mu[f] * iv;
      float cf  = NL2E * iv;
      civ2[f >> 1][f & 1]  = cf;
      cmiv2[f >> 1][f & 1] = -2.0f * mu[f] * cf;
    }
    c0 = NL2E * cst;
    cw = c0 + EMSC;
  }

  /* ---- softmax stats (max, 1/sum) of pi_logits row `lane` -> LDS ---- */
  {
    const float4* pr4 = reinterpret_cast<const float4*>(pi_logits + lane * K_N);
    float mx = -3.0e38f;
#pragma unroll
    for (int k = 0; k < 16; ++k) {
      float4 r = pr4[k];
      mx = fmaxf(mx, fmaxf(fmaxf(r.x, r.y), fmaxf(r.z, r.w)));
    }
    float s = 0.0f;
#pragma unroll
    for (int k = 0; k < 16; ++k) {
      float4 r = pr4[k];
      s += __builtin_amdgcn_exp2f((r.x - mx) * LOG2E);
      s += __builtin_amdgcn_exp2f((r.y - mx) * LOG2E);
      s += __builtin_amdgcn_exp2f((r.z - mx) * LOG2E);
      s += __builtin_amdgcn_exp2f((r.w - mx) * LOG2E);
    }
    sstat[lane] = make_float2(mx, RCP(s));
  }
  __syncthreads();

  /* ---- gather indices BY CONSTRUCTION: same DPP chain on lane id.
     ki[rr] = lane whose state lands in Gr[rr]; all within own 16-row. ---- */
  int ki[16];
  ki[0] = lane;
  ki[1] = DPPI(ki[0], 0xB1);
  ki[2] = DPPI(ki[0], 0x4E);
  ki[3] = DPPI(ki[1], 0x4E);
#pragma unroll
  for (int rr = 0; rr < 4; ++rr) ki[4 + rr] = DPPI(ki[rr], 0x124);
#pragma unroll
  for (int rr = 0; rr < 8; ++rr) ki[8 + rr] = DPPI(ki[rr], 0x128);

  /* Tq[d][j] = pair for columns {ki[2j], ki[2j+1]} of row (lane ^ 16d) */
  v2f Tq[4][8];

  if (bid < N_CH) {
    /* ================= FORWARD =================
       y[c] = sum_k v[k]*trans[k][c] => M = trans^T: M[r][k] = tn(k,r),
       softmax stats indexed by k (trans row). Preamble-only reads,
       pi_logits 16 KB L2-resident. */
#pragma unroll
    for (int j = 0; j < 8; ++j) {
      int k0 = ki[2 * j], k1 = ki[2 * j + 1];
      float2 s0 = sstat[k0], s1 = sstat[k1];
#pragma unroll
      for (int d = 0; d < 4; ++d) {
        int row = lane ^ (16 * d);
        float p0 = pi_logits[(size_t)k0 * K_N + row];
        float p1 = pi_logits[(size_t)k1 * K_N + row];
        Tq[d][j] = (v2f){__builtin_amdgcn_exp2f((p0 - s0.x) * LOG2E) * s0.y,
                         __builtin_amdgcn_exp2f((p1 - s1.x) * LOG2E) * s1.y};
      }
    }

    const int out_lo = bid * L_C;
    float v;
    int t_first;
    if (bid == 0) {
      /* exact stick-breaking init at RAW scale */
      float bl = beta_logits[lane];
      float ex = __builtin_amdgcn_exp2f(-bl * LOG2E);
      float bw = RCP(1.0f + ex);
      sb[lane] = 1.0f - bw;
      __syncthreads();
      float pr = 1.0f;
#pragma unroll
      for (int i = 0; i < 64; ++i) {
        float qv = sb[i];
        pr = (i < lane) ? pr * qv : pr;
      }
      float4 x0 = reinterpret_cast<const float4*>(obs)[0];
      float4 x1 = reinterpret_cast<const float4*>(obs)[1];
      v = bw * pr * em_pk(x0, x1, civ2, cmiv2, c0);
      t_first = 1;
    } else {
      const int t0 = out_lo - WARM;
      const float4* xp = reinterpret_cast<const float4*>(obs + t0 * F_N);
      v = em_pk(xp[0], xp[1], civ2, cmiv2, cw);
      t_first = t0 + 1;
    }
    int obs_off = t_first * F_N;
    float4 xa, xb;
    {
      const float4* xp = reinterpret_cast<const float4*>(obs + obs_off);
      xa = xp[0]; xb = xp[1];
    }
    int out_off = out_lo * K_N + lane;

    /* ---- warm-up: scale-free (scaled em), rescale every 8 ---- */
    const int wn8 = (bid == 0) ? 0 : (WARM >> 3);
#pragma unroll 1
    for (int o = 0; o < wn8; ++o) {
#pragma unroll
      for (int i = 0; i < 8; ++i) {
        float4 nxa = *reinterpret_cast<const float4*>(obs + obs_off + F_N);
        float4 nxb = *reinterpret_cast<const float4*>(obs + obs_off + F_N + 4);
        float m;
        MATVEC(v, m)
        float e = em_pk(xa, xb, civ2, cmiv2, cw);
        v = m * e;
        xa = nxa; xb = nxb; obs_off += F_N;
      }
      float Sw = wave_sum64(v);
      v *= RCP(Sw);
    }

    /* ---- store phase: RAW-scale em, reference EPS semantics ---- */
    float S = wave_sum64(v);
    float r_st = RCP(S + EPS_F);

#define FWD_SSTEP                                                             \
  {                                                                           \
    int offn = obs_off + F_N; offn = (offn > OBS_MAX) ? OBS_MAX : offn;       \
    float4 nxa = *reinterpret_cast<const float4*>(obs + offn);                \
    float4 nxb = *reinterpret_cast<const float4*>(obs + offn + 4);            \
    float m;                                                                  \
    MATVEC(v, m)                                                              \
    alpha[out_off] = v * r_st; out_off += K_N;                                \
    float e = em_pk(xa, xb, civ2, cmiv2, c0);                                 \
    float vn = m * (r_st * e);                                                \
    S = wave_sum64(vn);                                                       \
    r_st = RCP(S + EPS_F);                                                    \
    v = vn; xa = nxa; xb = nxb; obs_off = offn;                               \
  }

#pragma unroll 2
    for (int it = 0; it < L_C - 1; ++it) FWD_SSTEP
#undef FWD_SSTEP
    alpha[out_off] = v * r_st;
    if (bid == N_CH - 1 && lane == 0) {
      float sl = S * r_st + EPS_F;
      out[(size_t)2 * T_N * K_N] = __builtin_amdgcn_logf(sl) * LN2;
    }
  } else {
    /* ================= BACKWARD =================
       y[i] = sum_k trans[i][k]*w[k] => M = trans: M[r][k] = tn(r,k),
       stats indexed by r. */
#pragma unroll
    for (int d = 0; d < 4; ++d) {
      int row = lane ^ (16 * d);
      float2 st = sstat[row];
      const float* rp = pi_logits + (size_t)row * K_N;
#pragma unroll
      for (int j = 0; j < 8; ++j) {
        float p0 = rp[ki[2 * j]];
        float p1 = rp[ki[2 * j + 1]];
        Tq[d][j] = (v2f){__builtin_amdgcn_exp2f((p0 - st.x) * LOG2E) * st.y,
                         __builtin_amdgcn_exp2f((p1 - st.x) * LOG2E) * st.y};
      }
    }

    const int cb   = bid - N_CH;
    const int t_lo = cb * L_C;
    const int t_hi = t_lo + L_C - 1;
    int t_top = t_hi + WARM;
    if (t_top > T_N - 1) t_top = T_N - 1;        /* clamp => exact bT anchor */
    const int s_top = (cb == N_CH - 1) ? T_N - 2 : t_hi;

    float w;
    {
      const float4* xp = reinterpret_cast<const float4*>(obs + t_top * F_N);
      w = em_pk(xp[0], xp[1], civ2, cmiv2, cw);
    }
    if (cb == N_CH - 1)
      betaout[(size_t)(T_N - 1) * K_N + lane] = 1.0f;
    int obs_off = (t_top - 1) * F_N;
    float4 xa, xb;
    {
      const float4* xp = reinterpret_cast<const float4*>(obs + obs_off);
      xa = xp[0]; xb = xp[1];
    }
    int out_off = s_top * K_N + lane;

    /* ---- warm-up (scale-free, scaled em), pw = warm_n - 1 steps ---- */
#define BWD_WSTEP                                                             \
  {                                                                           \
    float4 nxa = *reinterpret_cast<const float4*>(obs + obs_off - F_N);       \
    float4 nxb = *reinterpret_cast<const float4*>(obs + obs_off - F_N + 4);   \
    float m;                                                                  \
    MATVEC(w, m)                                                              \
    float e = em_pk(xa, xb, civ2, cmiv2, cw);                                 \
    w = m * e;                                                                \
    xa = nxa; xb = nxb; obs_off -= F_N;                                       \
  }

    const int pw  = (t_top - s_top) - 1;         /* 31 generic, 0 last chunk */
    const int pw8 = pw >> 3, pwr = pw & 7;
#pragma unroll 1
    for (int o = 0; o < pw8; ++o) {
#pragma unroll
      for (int i = 0; i < 8; ++i) BWD_WSTEP
      float Sw = wave_sum64(w);
      w *= RCP(Sw);
    }
#pragma unroll 1
    for (int it = 0; it < pwr; ++it) BWD_WSTEP
#undef BWD_WSTEP

    /* ---- transition: exact direction normalize, switch to RAW-scale em ---- */
    float u, S, r_st;
    {
      float m;
      MATVEC(w, m)
      float Sm = wave_sum64(m);
      u = m * RCP(Sm);                            /* b(s_top), sum == 1 */
      float e = em_pk(xa, xb, civ2, cmiv2, c0);
      w = u * e;
      S = wave_sum64(u);
      r_st = RCP(S + EPS_F);
      int offn = obs_off - F_N; offn = (offn < 0) ? 0 : offn;
      xa = *reinterpret_cast<const float4*>(obs + offn);
      xb = *reinterpret_cast<const float4*>(obs + offn + 4);
      obs_off = offn;
    }

#define BWD_SSTEP                                                             \
  {                                                                           \
    int offn = obs_off - F_N; offn = (offn < 0) ? 0 : offn;                   \
    float4 nxa = *reinterpret_cast<const float4*>(obs + offn);                \
    float4 nxb = *reinterpret_cast<const float4*>(obs + offn + 4);            \
    float m;                                                                  \
    MATVEC(w, m)                                                              \
    betaout[out_off] = u * r_st; out_off -= K_N;                              \
    float u2 = m * r_st;                                                      \
    float e = em_pk(xa, xb, civ2, cmiv2, c0);                                 \
    w = u2 * e;                                                               \
    S = wave_sum64(u2);                                                       \
    r_st = RCP(S + EPS_F);                                                    \
    u = u2; xa = nxa; xb = nxb; obs_off = offn;                               \
  }

    const int store_n = s_top - t_lo;
#pragma unroll 2
    for (int it = 0; it < store_n; ++it) BWD_SSTEP
#undef BWD_SSTEP
    betaout[t_lo * K_N + lane] = u * r_st;
  }
}

extern "C" void kernel_launch(void* const* d_in, const int* in_sizes, int n_in,
                              void* d_out, int out_size, void* d_ws, size_t ws_size,
                              hipStream_t stream) {
  (void)in_sizes; (void)n_in; (void)out_size; (void)d_ws; (void)ws_size;
  const float* obs  = (const float*)d_in[0];
  const float* bl   = (const float*)d_in[1];
  const float* pi   = (const float*)d_in[2];
  const float* mns  = (const float*)d_in[3];
  const float* lvs  = (const float*)d_in[4];
  hipLaunchKernelGGL(hdphmm_fb, dim3(2 * N_CH), dim3(64), 0, stream,
                     obs, bl, pi, mns, lvs, (float*)d_out);
}